// Round 6
// baseline (164.003 us; speedup 1.0000x reference)
//
#include <hip/hip_runtime.h>
#include <math.h>

#define BB 64
#define HH 1024
#define VV 32000
#define SRC 128

typedef __attribute__((ext_vector_type(8))) __bf16 bf16x8;
typedef __attribute__((ext_vector_type(8))) unsigned short ushort8;
typedef __attribute__((ext_vector_type(4))) float f32x4;

__device__ __forceinline__ float sigmoidf_(float x){ return 1.f/(1.f+expf(-x)); }

__device__ __forceinline__ unsigned short f2bf(float f){
    union { float f; unsigned u; } v; v.f = f;
    unsigned r = v.u + 0x7FFFu + ((v.u >> 16) & 1u);   // round-to-nearest-even
    return (unsigned short)(r >> 16);
}

__device__ __forceinline__ void cvt8(const float4& x, const float4& y, unsigned short* dst){
    ushort8 s;
    s[0]=f2bf(x.x); s[1]=f2bf(x.y); s[2]=f2bf(x.z); s[3]=f2bf(x.w);
    s[4]=f2bf(y.x); s[5]=f2bf(y.y); s[6]=f2bf(y.z); s[7]=f2bf(y.w);
    *(ushort8*)dst = s;
}

// ============ MFMA GEMM: C[64,N] = A[64,K] @ W[N,K]^T (fp32 in, bf16 mfma) ============
// Tile 64M x 128N, BK=64, 256 threads (4 waves, each wave a 32-wide N strip).
// W split into two row-major arrays at global-k K0 (for [W_ih|W_hh]); kChunk % 64 == 0,
// K0 % kChunk == 0. grid = (N/128, S).  EPI: 0 raw partial (+by*64*N), 1 +bias, 2 +bias,tanh
template<int EPI>
__global__ __launch_bounds__(256)
void gemm_bf(const float* __restrict__ A, int lda,
             const float* __restrict__ B0, const float* __restrict__ B1,
             int K0, int ldb, int kChunk, int N,
             const float* __restrict__ bias, float* __restrict__ C)
{
    // padded row stride 72 shorts (144 B): 16B-aligned rows, 2-way-max bank aliasing
    __shared__ __align__(16) unsigned short As[64*72];
    __shared__ __align__(16) unsigned short Bs[128*72];
    const int tid = threadIdx.x;
    const int n0 = blockIdx.x * 128;
    const int kbase = blockIdx.y * kChunk;
    const int nt = kChunk >> 6;

    const int am = tid >> 2, ak = (tid & 3) << 4;   // A stage: row, 16-float k chunk
    const int bn = tid >> 1, bk = (tid & 1) << 5;   // B stage: row, 32-float k chunk

    f32x4 acc[4][2] = {};
    float4 aR[4], bR[8];

    auto loadG = [&](int t){
        int k0g = kbase + (t << 6);
        const float* Ap = A + (size_t)am * lda + k0g + ak;
        #pragma unroll
        for (int i = 0; i < 4; ++i) aR[i] = *(const float4*)(Ap + i*4);
        const float* Bp; int kb;
        if (k0g < K0) { Bp = B0; kb = k0g; } else { Bp = B1; kb = k0g - K0; }
        const float* Bq = Bp + (size_t)(n0 + bn) * ldb + kb + bk;
        #pragma unroll
        for (int i = 0; i < 8; ++i) bR[i] = *(const float4*)(Bq + i*4);
    };
    auto writeL = [&](){
        cvt8(aR[0], aR[1], &As[am*72 + ak]);
        cvt8(aR[2], aR[3], &As[am*72 + ak + 8]);
        #pragma unroll
        for (int h = 0; h < 4; ++h)
            cvt8(bR[h*2], bR[h*2+1], &Bs[bn*72 + bk + h*8]);
    };

    loadG(0);
    writeL();
    __syncthreads();

    const int lane = tid & 63;
    const int wn = (tid >> 6) << 5;           // wave's 32-wide N strip: 0,32,64,96
    const int lr = lane >> 4, lc = lane & 15; // k-group / row-col within fragment

    for (int t = 0; t < nt; ++t) {
        if (t + 1 < nt) loadG(t + 1);         // prefetch next tile (global, fp32)
        #pragma unroll
        for (int ks = 0; ks < 2; ++ks) {      // two K=32 mfma steps per BK=64 tile
            bf16x8 aF[4], bF[2];
            #pragma unroll
            for (int fm = 0; fm < 4; ++fm)
                aF[fm] = *(const bf16x8*)&As[(fm*16 + lc)*72 + ks*32 + lr*8];
            #pragma unroll
            for (int fn = 0; fn < 2; ++fn)
                bF[fn] = *(const bf16x8*)&Bs[(wn + fn*16 + lc)*72 + ks*32 + lr*8];
            #pragma unroll
            for (int fm = 0; fm < 4; ++fm)
                #pragma unroll
                for (int fn = 0; fn < 2; ++fn)
                    acc[fm][fn] = __builtin_amdgcn_mfma_f32_16x16x32_bf16(
                        aF[fm], bF[fn], acc[fm][fn], 0, 0, 0);
        }
        __syncthreads();
        if (t + 1 < nt) { writeL(); __syncthreads(); }
    }

    float* Cp = (EPI == 0) ? (C + (size_t)blockIdx.y * 64 * N) : C;
    #pragma unroll
    for (int fn = 0; fn < 2; ++fn) {
        int n = n0 + wn + fn*16 + lc;
        float bv = (EPI >= 1) ? bias[n] : 0.f;
        #pragma unroll
        for (int fm = 0; fm < 4; ++fm) {
            #pragma unroll
            for (int r = 0; r < 4; ++r) {
                int m = fm*16 + lr*4 + r;     // D: col = lane&15, row = (lane>>4)*4+r
                float v = acc[fm][fn][r] + bv;
                if (EPI == 2) v = tanhf(v);
                Cp[(size_t)m*N + n] = v;
            }
        }
    }
}

// ---------------- embedding gather + A_cat prep ----------------
__global__ __launch_bounds__(256)
void prep_kernel(const int* __restrict__ tokens, const float* __restrict__ emb,
                 const float* __restrict__ h0,
                 float* __restrict__ Acat0, float* __restrict__ Acat1)
{
    int idx = blockIdx.x*256 + threadIdx.x;     // 0..65535
    int b = idx >> 10, k = idx & 1023;
    int tok = tokens[b];
    Acat0[b*2048 + k]        = emb[(size_t)tok*HH + k];
    Acat0[b*2048 + 1024 + k] = h0[b*HH + k];                 // h0[0]
    Acat1[b*2048 + 1024 + k] = h0[BB*HH + b*HH + k];         // h0[1]
}

// ---------------- LSTM pointwise (sums SLSTM=8 split-K partials) ----------------
#define SLSTM 8
__global__ __launch_bounds__(256)
void lstm_point(const float* __restrict__ gates,   // [SLSTM][64][4096]
                const float* __restrict__ bih, const float* __restrict__ bhh,
                const float* __restrict__ c0,
                float* __restrict__ hn, float* __restrict__ cn,
                float* __restrict__ hA, int hAoff)
{
    int idx = blockIdx.x*256 + threadIdx.x;     // 0..65535
    int b = idx >> 10, k = idx & 1023;
    const float* g = gates + b*4096;
    float ig = bih[k]        + bhh[k];
    float fg = bih[1024 + k] + bhh[1024 + k];
    float gg = bih[2048 + k] + bhh[2048 + k];
    float og = bih[3072 + k] + bhh[3072 + k];
    #pragma unroll
    for (int s = 0; s < SLSTM; ++s) {
        const float* gs = g + s*BB*4096;
        ig += gs[k];
        fg += gs[1024 + k];
        gg += gs[2048 + k];
        og += gs[3072 + k];
    }
    float c = sigmoidf_(fg)*c0[b*HH + k] + sigmoidf_(ig)*tanhf(gg);
    float h = sigmoidf_(og)*tanhf(c);
    cn[b*HH + k] = c;
    hn[b*HH + k] = h;
    hA[b*2048 + hAoff + k] = h;
}

// ---------------- concat reduce + bias + tanh (SCAT=8 partials) ----------------
#define SCAT 8
__global__ __launch_bounds__(256)
void reduce_tanh(const float* __restrict__ P,   // [SCAT][64][1024]
                 const float* __restrict__ bias, float* __restrict__ out)
{
    int idx = blockIdx.x*256 + threadIdx.x;     // 0..65535
    int n = idx & 1023;
    float s = bias[n];
    #pragma unroll
    for (int si = 0; si < SCAT; ++si) s += P[si*65536 + idx];
    out[idx] = tanhf(s);
}

// ---------------- attention: u = attn_W^T v ; c_s = v . attn_b ----------------
__global__ __launch_bounds__(256)
void attn_u_kernel(const float* __restrict__ attn_W, const float* __restrict__ attn_v,
                   const float* __restrict__ attn_b,
                   float* __restrict__ u, float* __restrict__ c_s)
{
    if (blockIdx.x < 32) {
        __shared__ float4 red[16][17];
        int kq = threadIdx.x & 15;
        int hp = threadIdx.x >> 4;
        int k = blockIdx.x*64 + kq*4;
        float4 s = {0.f,0.f,0.f,0.f};
        for (int h = hp; h < HH; h += 16) {
            float vh = attn_v[h];
            float4 w = *(const float4*)&attn_W[(size_t)h*2048 + k];
            s.x = fmaf(vh, w.x, s.x);
            s.y = fmaf(vh, w.y, s.y);
            s.z = fmaf(vh, w.z, s.z);
            s.w = fmaf(vh, w.w, s.w);
        }
        red[hp][kq] = s;
        __syncthreads();
        if (threadIdx.x < 16) {
            float4 t = {0.f,0.f,0.f,0.f};
            #pragma unroll
            for (int i=0;i<16;++i) {
                float4 r = red[i][threadIdx.x];
                t.x += r.x; t.y += r.y; t.z += r.z; t.w += r.w;
            }
            *(float4*)&u[blockIdx.x*64 + threadIdx.x*4] = t;
        }
    } else {
        __shared__ float red[256];
        float s = 0.f;
        for (int h = threadIdx.x; h < HH; h += 256) s = fmaf(attn_v[h], attn_b[h], s);
        red[threadIdx.x] = s; __syncthreads();
        for (int o = 128; o > 0; o >>= 1) {
            if (threadIdx.x < o) red[threadIdx.x] += red[threadIdx.x + o];
            __syncthreads();
        }
        if (threadIdx.x == 0) *c_s = red[0];
    }
}

// ---------------- d_h[b] = u_h . h_top[b] ----------------
__global__ __launch_bounds__(256)
void dh_kernel(const float* __restrict__ u, const float* __restrict__ Acat3,
               float* __restrict__ d_h)
{
    int b = blockIdx.x;
    __shared__ float red[256];
    float s = 0.f;
    for (int k = threadIdx.x*4; k < HH; k += 1024) {
        float4 uu = *(const float4*)&u[k];
        float4 hh = *(const float4*)&Acat3[b*2048 + 1024 + k];
        s = fmaf(uu.x, hh.x, s); s = fmaf(uu.y, hh.y, s);
        s = fmaf(uu.z, hh.z, s); s = fmaf(uu.w, hh.w, s);
    }
    red[threadIdx.x] = s; __syncthreads();
    for (int o = 128; o > 0; o >>= 1) {
        if (threadIdx.x < o) red[threadIdx.x] += red[threadIdx.x + o];
        __syncthreads();
    }
    if (threadIdx.x == 0) d_h[b] = red[0];
}

// ---------------- scores[b,l] = u_e . enc[l,b,:] + d_h[b] + c_s ----------------
__global__ __launch_bounds__(256)
void scores_kernel(const float* __restrict__ u, const float* __restrict__ enc,
                   const float* __restrict__ d_h, const float* __restrict__ c_s,
                   float* __restrict__ scores)
{
    int w    = blockIdx.x*4 + (threadIdx.x >> 6);   // 0..8191
    int lane = threadIdx.x & 63;
    int b = w >> 7, l = w & 127;
    const float* e = enc + (size_t)(l*BB + b)*HH;
    const float* ue = u + 1024;
    float s = 0.f;
    #pragma unroll
    for (int t = 0; t < 16; ++t)
        s = fmaf(ue[lane + 64*t], e[lane + 64*t], s);
    #pragma unroll
    for (int o = 32; o > 0; o >>= 1) s += __shfl_xor(s, o);
    if (lane == 0) scores[b*SRC + l] = s + d_h[b] + *c_s;
}

// ---------------- softmax over l (128) per b ----------------
__global__ __launch_bounds__(64)
void softmax_kernel(const float* __restrict__ scores, float* __restrict__ w)
{
    int b = blockIdx.x, lane = threadIdx.x;
    float s0 = scores[b*SRC + lane], s1 = scores[b*SRC + 64 + lane];
    float m = fmaxf(s0, s1);
    #pragma unroll
    for (int o = 32; o > 0; o >>= 1) m = fmaxf(m, __shfl_xor(m, o));
    float e0 = expf(s0 - m), e1 = expf(s1 - m);
    float sum = e0 + e1;
    #pragma unroll
    for (int o = 32; o > 0; o >>= 1) sum += __shfl_xor(sum, o);
    float inv = 1.f / sum;
    w[b*SRC + lane]      = e0 * inv;
    w[b*SRC + 64 + lane] = e1 * inv;
}

// ---------------- context[b,h] = sum_l w[b,l] enc[l,b,h] ----------------
__global__ __launch_bounds__(256)
void context_kernel(const float* __restrict__ w, const float* __restrict__ enc,
                    float* __restrict__ Acat3)
{
    int idx = blockIdx.x*256 + threadIdx.x;     // 0..65535
    int b = idx >> 10, h = idx & 1023;
    float s = 0.f;
    #pragma unroll 4
    for (int l = 0; l < SRC; ++l)
        s = fmaf(w[b*SRC + l], enc[(size_t)(l*BB + b)*HH + h], s);
    Acat3[b*2048 + h] = s;
}

// ---------------- log-sum-exp per row of logits (float4) ----------------
__global__ __launch_bounds__(256)
void lse_kernel(const float* __restrict__ logits, float* __restrict__ lse)
{
    int b = blockIdx.x;
    __shared__ float red[256];
    const float4* row = (const float4*)(logits + (size_t)b*VV);  // 8000 float4
    float m = -INFINITY;
    for (int i = threadIdx.x; i < 8000; i += 256) {
        float4 v = row[i];
        m = fmaxf(m, fmaxf(fmaxf(v.x, v.y), fmaxf(v.z, v.w)));
    }
    red[threadIdx.x] = m; __syncthreads();
    for (int o = 128; o > 0; o >>= 1) {
        if (threadIdx.x < o) red[threadIdx.x] = fmaxf(red[threadIdx.x], red[threadIdx.x + o]);
        __syncthreads();
    }
    m = red[0]; __syncthreads();
    float s = 0.f;
    for (int i = threadIdx.x; i < 8000; i += 256) {
        float4 v = row[i];
        s += expf(v.x - m) + expf(v.y - m) + expf(v.z - m) + expf(v.w - m);
    }
    red[threadIdx.x] = s; __syncthreads();
    for (int o = 128; o > 0; o >>= 1) {
        if (threadIdx.x < o) red[threadIdx.x] += red[threadIdx.x + o];
        __syncthreads();
    }
    if (threadIdx.x == 0) lse[b] = m + logf(red[0]);
}

__global__ __launch_bounds__(256)
void sub_kernel(float* __restrict__ logp, const float* __restrict__ lse)
{
    int b = blockIdx.y;
    int i = blockIdx.x*256 + threadIdx.x;       // over 8000 float4
    if (i < 8000) {
        float4* p = (float4*)(logp + (size_t)b*VV);
        float4 v = p[i];
        float l = lse[b];
        v.x -= l; v.y -= l; v.z -= l; v.w -= l;
        p[i] = v;
    }
}

// ================================================================
extern "C" void kernel_launch(void* const* d_in, const int* in_sizes, int n_in,
                              void* d_out, int out_size, void* d_ws, size_t ws_size,
                              hipStream_t stream)
{
    const int*   tokens   = (const int*)  d_in[0];
    const float* h0       = (const float*)d_in[1];
    const float* c0       = (const float*)d_in[2];
    const float* enc      = (const float*)d_in[3];
    const float* emb      = (const float*)d_in[4];
    const float* W_ih     = (const float*)d_in[5];
    const float* W_hh     = (const float*)d_in[6];
    const float* b_ih     = (const float*)d_in[7];
    const float* b_hh     = (const float*)d_in[8];
    const float* attn_W   = (const float*)d_in[9];
    const float* attn_b   = (const float*)d_in[10];
    const float* attn_v   = (const float*)d_in[11];
    const float* concat_W = (const float*)d_in[12];
    const float* concat_b = (const float*)d_in[13];
    const float* out_W    = (const float*)d_in[14];
    const float* out_b    = (const float*)d_in[15];

    float* out  = (float*)d_out;
    float* logp = out;                      // [64, 32000]
    float* h_n  = out + (size_t)BB*VV;      // [2, 64, 1024]
    float* c_n  = h_n + 2*BB*HH;            // [2, 64, 1024]

    // workspace layout (floats)
    float* ws     = (float*)d_ws;
    float* Acat0  = ws;                       // [64, 2048]  = [emb ; h0[0]]
    float* Acat1  = Acat0 + 131072;           // [64, 2048]  = [h1 ; h0[1]]
    float* Acat3  = Acat1 + 131072;           // [64, 2048]  = [context ; h_top]
    float* gates  = Acat3 + 131072;           // [SLSTM=8][64, 4096] partials
    float* catP   = gates;                    // [SCAT=8][64, 1024] (aliases gates; disjoint lifetime)
    float* h_c    = gates + SLSTM*262144;     // [64, 1024]
    float* u      = h_c   + 65536;            // [2048]
    float* c_s    = u     + 2048;             // [1]
    float* d_h    = c_s   + 4;                // [64]
    float* scores = d_h   + 64;               // [64, 128]
    float* attw   = scores+ 8192;             // [64, 128]
    float* lse    = attw  + 8192;             // [64]

    // 1) embedding gather + A_cat prep
    prep_kernel<<<256, 256, 0, stream>>>(tokens, emb, h0, Acat0, Acat1);

    // 2) LSTM layer 0: gates = Acat0 @ [W_ih0 | W_hh0]^T  (split-K S=8, kChunk=256)
    gemm_bf<0><<<dim3(32, SLSTM), 256, 0, stream>>>(Acat0, 2048,
                                      W_ih, W_hh, 1024, 1024,
                                      256, 4096, nullptr, gates);
    lstm_point<<<256, 256, 0, stream>>>(gates, b_ih, b_hh, c0,
                                        h_n, c_n, Acat1, 0);

    // 3) LSTM layer 1
    gemm_bf<0><<<dim3(32, SLSTM), 256, 0, stream>>>(Acat1, 2048,
                                      W_ih + (size_t)4096*1024,
                                      W_hh + (size_t)4096*1024, 1024, 1024,
                                      256, 4096, nullptr, gates);
    lstm_point<<<256, 256, 0, stream>>>(gates, b_ih + 4096, b_hh + 4096, c0 + BB*HH,
                                        h_n + BB*HH, c_n + BB*HH, Acat3, 1024);

    // 4) attention folded vector u = attn_W^T v, scalar c_s = v.b
    attn_u_kernel<<<33, 256, 0, stream>>>(attn_W, attn_v, attn_b, u, c_s);

    // 5) d_h[b] = u_h . h_top[b]
    dh_kernel<<<64, 256, 0, stream>>>(u, Acat3, d_h);

    // 6) scores + softmax + context
    scores_kernel<<<2048, 256, 0, stream>>>(u, enc, d_h, c_s, scores);
    softmax_kernel<<<64, 64, 0, stream>>>(scores, attw);
    context_kernel<<<256, 256, 0, stream>>>(attw, enc, Acat3);

    // 7) concat partials = Acat3 @ concat_W^T  (split-K S=8, kChunk=256)
    gemm_bf<0><<<dim3(8, SCAT), 256, 0, stream>>>(Acat3, 2048,
                                      concat_W, nullptr, 1 << 30, 2048,
                                      256, 1024, nullptr, catP);
    reduce_tanh<<<256, 256, 0, stream>>>(catP, concat_b, h_c);

    // 8) logits = h_c @ out_W^T + out_b  (250 blocks, no split)
    gemm_bf<1><<<dim3(250, 1), 256, 0, stream>>>(h_c, 1024,
                                      out_W, nullptr, 1 << 30, 1024,
                                      1024, VV, out_b, logp);

    // 9) log-softmax
    lse_kernel<<<64, 256, 0, stream>>>(logp, lse);
    sub_kernel<<<dim3(32, 64), 256, 0, stream>>>(logp, lse);
}

// Round 7
// 153.692 us; speedup vs baseline: 1.0671x; 1.0671x over previous
//
#include <hip/hip_runtime.h>
#include <math.h>

#define BB 64
#define HH 1024
#define VV 32000
#define SRC 128

typedef __attribute__((ext_vector_type(8))) __bf16 bf16x8;
typedef __attribute__((ext_vector_type(8))) unsigned short ushort8;
typedef __attribute__((ext_vector_type(4))) float f32x4;

__device__ __forceinline__ float sigmoidf_(float x){ return 1.f/(1.f+expf(-x)); }

__device__ __forceinline__ unsigned short f2bf(float f){
    union { float f; unsigned u; } v; v.f = f;
    unsigned r = v.u + 0x7FFFu + ((v.u >> 16) & 1u);   // round-to-nearest-even
    return (unsigned short)(r >> 16);
}

__device__ __forceinline__ void cvt8(const float4& x, const float4& y, unsigned short* dst){
    ushort8 s;
    s[0]=f2bf(x.x); s[1]=f2bf(x.y); s[2]=f2bf(x.z); s[3]=f2bf(x.w);
    s[4]=f2bf(y.x); s[5]=f2bf(y.y); s[6]=f2bf(y.z); s[7]=f2bf(y.w);
    *(ushort8*)dst = s;
}

// ============ MFMA GEMM: C[64,N] = A[64,K] @ W[N,K]^T (fp32 in, bf16 mfma) ============
// Tile 64M x 128N, BK=64, 256 threads (4 waves). LDS double-buffered: ONE barrier/tile,
// global loads for t+1 issued before compute(t). W split at global-k K0 ([W_ih|W_hh]).
// kChunk % 64 == 0, K0 % kChunk == 0. grid = (N/128, S).
// EPI: 0 raw partial (+by*64*N), 1 +bias
template<int EPI>
__global__ __launch_bounds__(256)
void gemm_bf(const float* __restrict__ A, int lda,
             const float* __restrict__ B0, const float* __restrict__ B1,
             int K0, int ldb, int kChunk, int N,
             const float* __restrict__ bias, float* __restrict__ C)
{
    // padded row stride 72 shorts (144 B): 16B-aligned rows, 2-way-max bank aliasing
    __shared__ __align__(16) unsigned short As[2][64*72];
    __shared__ __align__(16) unsigned short Bs[2][128*72];
    const int tid = threadIdx.x;
    const int n0 = blockIdx.x * 128;
    const int kbase = blockIdx.y * kChunk;
    const int nt = kChunk >> 6;

    const int am = tid >> 2, ak = (tid & 3) << 4;   // A stage: row, 16-float k chunk
    const int bn = tid >> 1, bk = (tid & 1) << 5;   // B stage: row, 32-float k chunk

    f32x4 acc[4][2] = {};
    float4 aR[4], bR[8];

    auto loadG = [&](int t){
        int k0g = kbase + (t << 6);
        const float* Ap = A + (size_t)am * lda + k0g + ak;
        #pragma unroll
        for (int i = 0; i < 4; ++i) aR[i] = *(const float4*)(Ap + i*4);
        const float* Bp; int kb;
        if (k0g < K0) { Bp = B0; kb = k0g; } else { Bp = B1; kb = k0g - K0; }
        const float* Bq = Bp + (size_t)(n0 + bn) * ldb + kb + bk;
        #pragma unroll
        for (int i = 0; i < 8; ++i) bR[i] = *(const float4*)(Bq + i*4);
    };
    auto writeL = [&](int buf){
        cvt8(aR[0], aR[1], &As[buf][am*72 + ak]);
        cvt8(aR[2], aR[3], &As[buf][am*72 + ak + 8]);
        #pragma unroll
        for (int h = 0; h < 4; ++h)
            cvt8(bR[h*2], bR[h*2+1], &Bs[buf][bn*72 + bk + h*8]);
    };

    loadG(0);
    writeL(0);
    __syncthreads();

    const int lane = tid & 63;
    const int wn = (tid >> 6) << 5;           // wave's 32-wide N strip: 0,32,64,96
    const int lr = lane >> 4, lc = lane & 15;

    for (int t = 0; t < nt; ++t) {
        const int cur = t & 1;
        if (t + 1 < nt) loadG(t + 1);         // in flight across the whole compute below
        #pragma unroll
        for (int ks = 0; ks < 2; ++ks) {
            bf16x8 aF[4], bF[2];
            #pragma unroll
            for (int fm = 0; fm < 4; ++fm)
                aF[fm] = *(const bf16x8*)&As[cur][(fm*16 + lc)*72 + ks*32 + lr*8];
            #pragma unroll
            for (int fn = 0; fn < 2; ++fn)
                bF[fn] = *(const bf16x8*)&Bs[cur][(wn + fn*16 + lc)*72 + ks*32 + lr*8];
            #pragma unroll
            for (int fm = 0; fm < 4; ++fm)
                #pragma unroll
                for (int fn = 0; fn < 2; ++fn)
                    acc[fm][fn] = __builtin_amdgcn_mfma_f32_16x16x32_bf16(
                        aF[fm], bF[fn], acc[fm][fn], 0, 0, 0);
        }
        if (t + 1 < nt) {
            writeL((t + 1) & 1);              // writes the OTHER buffer; safe pre-barrier
            __syncthreads();                  // single barrier per tile
        }
    }

    float* Cp = (EPI == 0) ? (C + (size_t)blockIdx.y * 64 * N) : C;
    #pragma unroll
    for (int fn = 0; fn < 2; ++fn) {
        int n = n0 + wn + fn*16 + lc;
        float bv = (EPI >= 1) ? bias[n] : 0.f;
        #pragma unroll
        for (int fm = 0; fm < 4; ++fm) {
            #pragma unroll
            for (int r = 0; r < 4; ++r) {
                int m = fm*16 + lr*4 + r;     // D: col = lane&15, row = (lane>>4)*4+r
                Cp[(size_t)m*N + n] = acc[fm][fn][r] + bv;
            }
        }
    }
}

// ------------- embedding gather + A_cat prep + u_e = (attn_W^T v)[1024:2048] -------------
// Note: softmax_l(u_e.e + u_h.h + v.b) == softmax_l(u_e.e) — h/bias terms are constant
// over l and cancel exactly, so only the encoder half of u is needed.
__global__ __launch_bounds__(256)
void prep_attn(const int* __restrict__ tokens, const float* __restrict__ emb,
               const float* __restrict__ h0,
               const float* __restrict__ attn_W, const float* __restrict__ attn_v,
               float* __restrict__ Acat0, float* __restrict__ Acat1,
               float* __restrict__ u_e)
{
    if (blockIdx.x < 256) {
        int idx = blockIdx.x*256 + threadIdx.x;     // 0..65535
        int b = idx >> 10, k = idx & 1023;
        int tok = tokens[b];
        Acat0[b*2048 + k]        = emb[(size_t)tok*HH + k];
        Acat0[b*2048 + 1024 + k] = h0[b*HH + k];                 // h0[0]
        Acat1[b*2048 + 1024 + k] = h0[BB*HH + b*HH + k];         // h0[1]
    } else {
        __shared__ float4 red[16][17];
        int blk = blockIdx.x - 256;     // 0..15 -> 64 k's each
        int kq = threadIdx.x & 15;
        int hp = threadIdx.x >> 4;
        int k = 1024 + blk*64 + kq*4;
        float4 s = {0.f,0.f,0.f,0.f};
        for (int h = hp; h < HH; h += 16) {
            float vh = attn_v[h];
            float4 w = *(const float4*)&attn_W[(size_t)h*2048 + k];
            s.x = fmaf(vh, w.x, s.x);
            s.y = fmaf(vh, w.y, s.y);
            s.z = fmaf(vh, w.z, s.z);
            s.w = fmaf(vh, w.w, s.w);
        }
        red[hp][kq] = s;
        __syncthreads();
        if (threadIdx.x < 16) {
            float4 t = {0.f,0.f,0.f,0.f};
            #pragma unroll
            for (int i=0;i<16;++i) {
                float4 r = red[i][threadIdx.x];
                t.x += r.x; t.y += r.y; t.z += r.z; t.w += r.w;
            }
            *(float4*)&u_e[blk*64 + threadIdx.x*4] = t;
        }
    }
}

// ---------------- LSTM pointwise (sums SLSTM=8 split-K partials) ----------------
#define SLSTM 8
__global__ __launch_bounds__(256)
void lstm_point(const float* __restrict__ gates,   // [SLSTM][64][4096]
                const float* __restrict__ bih, const float* __restrict__ bhh,
                const float* __restrict__ c0,
                float* __restrict__ hn, float* __restrict__ cn,
                float* __restrict__ hA, int hAoff)
{
    int idx = blockIdx.x*256 + threadIdx.x;     // 0..65535
    int b = idx >> 10, k = idx & 1023;
    const float* g = gates + b*4096;
    float ig = bih[k]        + bhh[k];
    float fg = bih[1024 + k] + bhh[1024 + k];
    float gg = bih[2048 + k] + bhh[2048 + k];
    float og = bih[3072 + k] + bhh[3072 + k];
    #pragma unroll
    for (int s = 0; s < SLSTM; ++s) {
        const float* gs = g + s*BB*4096;
        ig += gs[k];
        fg += gs[1024 + k];
        gg += gs[2048 + k];
        og += gs[3072 + k];
    }
    float c = sigmoidf_(fg)*c0[b*HH + k] + sigmoidf_(ig)*tanhf(gg);
    float h = sigmoidf_(og)*tanhf(c);
    cn[b*HH + k] = c;
    hn[b*HH + k] = h;
    hA[b*2048 + hAoff + k] = h;
}

// ---------------- concat reduce + bias + tanh (SCAT=8 partials) ----------------
#define SCAT 8
__global__ __launch_bounds__(256)
void reduce_tanh(const float* __restrict__ P,   // [SCAT][64][1024]
                 const float* __restrict__ bias, float* __restrict__ out)
{
    int idx = blockIdx.x*256 + threadIdx.x;     // 0..65535
    int n = idx & 1023;
    float s = bias[n];
    #pragma unroll
    for (int si = 0; si < SCAT; ++si) s += P[si*65536 + idx];
    out[idx] = tanhf(s);
}

// ---------------- scores[b,l] = u_e . enc[l,b,:]  (bias terms cancel in softmax) ----------
__global__ __launch_bounds__(256)
void scores_kernel(const float* __restrict__ u_e, const float* __restrict__ enc,
                   float* __restrict__ scores)
{
    int w    = blockIdx.x*4 + (threadIdx.x >> 6);   // 0..8191
    int lane = threadIdx.x & 63;
    int b = w >> 7, l = w & 127;
    const float* e = enc + (size_t)(l*BB + b)*HH;
    float s = 0.f;
    #pragma unroll
    for (int t = 0; t < 16; ++t)
        s = fmaf(u_e[lane + 64*t], e[lane + 64*t], s);
    #pragma unroll
    for (int o = 32; o > 0; o >>= 1) s += __shfl_xor(s, o);
    if (lane == 0) scores[b*SRC + l] = s;
}

// -------- fused softmax(scores[b,:]) + context[b,h] = sum_l w_l enc[l,b,h] --------
// grid: 64 b x 4 h-chunks of 256
__global__ __launch_bounds__(256)
void smctx_kernel(const float* __restrict__ scores, const float* __restrict__ enc,
                  float* __restrict__ Acat3)
{
    __shared__ float wl[SRC];
    int b = blockIdx.x >> 2;
    int h = ((blockIdx.x & 3) << 8) + threadIdx.x;
    if (threadIdx.x < SRC) wl[threadIdx.x] = scores[b*SRC + threadIdx.x];
    __syncthreads();
    float m = -INFINITY;
    #pragma unroll 8
    for (int l = 0; l < SRC; ++l) m = fmaxf(m, wl[l]);       // LDS broadcast reads
    float sum = 0.f;
    #pragma unroll 8
    for (int l = 0; l < SRC; ++l) sum += expf(wl[l] - m);
    float inv = 1.f / sum;
    __syncthreads();
    if (threadIdx.x < SRC) wl[threadIdx.x] = expf(wl[threadIdx.x] - m) * inv;
    __syncthreads();
    float acc = 0.f;
    #pragma unroll 4
    for (int l = 0; l < SRC; ++l)
        acc = fmaf(wl[l], enc[(size_t)(l*BB + b)*HH + h], acc);
    Acat3[b*2048 + h] = acc;
}

// ------- logits = P0 + P1 + bias (split-K S=2 reduce), write to d_out, partial lse -------
// grid (4 chunks of 8000, 64 b)
__global__ __launch_bounds__(256)
void lse_part(const float* __restrict__ P, const float* __restrict__ bias,
              float* __restrict__ logits, float2* __restrict__ ms)
{
    int b = blockIdx.y, ch = blockIdx.x;
    const float4* p0 = (const float4*)(P + (size_t)b*VV)        + ch*2000;
    const float4* p1 = (const float4*)(P + (size_t)(BB + b)*VV) + ch*2000;
    const float4* bi = (const float4*)bias + ch*2000;
    float4* lg = (float4*)(logits + (size_t)b*VV) + ch*2000;
    __shared__ float red[256];
    float m = -INFINITY;
    for (int i = threadIdx.x; i < 2000; i += 256) {
        float4 a = p0[i], c = p1[i], d = bi[i];
        float4 v;
        v.x = a.x + c.x + d.x; v.y = a.y + c.y + d.y;
        v.z = a.z + c.z + d.z; v.w = a.w + c.w + d.w;
        lg[i] = v;
        m = fmaxf(m, fmaxf(fmaxf(v.x, v.y), fmaxf(v.z, v.w)));
    }
    red[threadIdx.x] = m; __syncthreads();
    for (int o = 128; o > 0; o >>= 1) {
        if (threadIdx.x < o) red[threadIdx.x] = fmaxf(red[threadIdx.x], red[threadIdx.x + o]);
        __syncthreads();
    }
    m = red[0]; __syncthreads();
    float s = 0.f;
    for (int i = threadIdx.x; i < 2000; i += 256) {
        float4 v = lg[i];                     // L2-hot re-read
        s += expf(v.x - m) + expf(v.y - m) + expf(v.z - m) + expf(v.w - m);
    }
    red[threadIdx.x] = s; __syncthreads();
    for (int o = 128; o > 0; o >>= 1) {
        if (threadIdx.x < o) red[threadIdx.x] += red[threadIdx.x + o];
        __syncthreads();
    }
    if (threadIdx.x == 0) ms[b*4 + ch] = make_float2(m, red[0]);
}

// ---------------- combine 4 (m,s) partials -> lse, subtract in place ----------------
__global__ __launch_bounds__(256)
void sub_final(float* __restrict__ logp, const float2* __restrict__ ms)
{
    int b = blockIdx.y;
    float2 a0 = ms[b*4], a1 = ms[b*4+1], a2 = ms[b*4+2], a3 = ms[b*4+3];
    float M = fmaxf(fmaxf(a0.x, a1.x), fmaxf(a2.x, a3.x));
    float S = a0.y*expf(a0.x - M) + a1.y*expf(a1.x - M)
            + a2.y*expf(a2.x - M) + a3.y*expf(a3.x - M);
    float lse = M + logf(S);
    int i = blockIdx.x*256 + threadIdx.x;
    if (i < 8000) {
        float4* p = (float4*)(logp + (size_t)b*VV);
        float4 v = p[i];
        v.x -= lse; v.y -= lse; v.z -= lse; v.w -= lse;
        p[i] = v;
    }
}

// ================================================================
extern "C" void kernel_launch(void* const* d_in, const int* in_sizes, int n_in,
                              void* d_out, int out_size, void* d_ws, size_t ws_size,
                              hipStream_t stream)
{
    const int*   tokens   = (const int*)  d_in[0];
    const float* h0       = (const float*)d_in[1];
    const float* c0       = (const float*)d_in[2];
    const float* enc      = (const float*)d_in[3];
    const float* emb      = (const float*)d_in[4];
    const float* W_ih     = (const float*)d_in[5];
    const float* W_hh     = (const float*)d_in[6];
    const float* b_ih     = (const float*)d_in[7];
    const float* b_hh     = (const float*)d_in[8];
    const float* attn_W   = (const float*)d_in[9];
    const float* attn_v   = (const float*)d_in[11];
    const float* concat_W = (const float*)d_in[12];
    const float* concat_b = (const float*)d_in[13];
    const float* out_W    = (const float*)d_in[14];
    const float* out_b    = (const float*)d_in[15];

    float* out  = (float*)d_out;
    float* logp = out;                      // [64, 32000]
    float* h_n  = out + (size_t)BB*VV;      // [2, 64, 1024]
    float* c_n  = h_n + 2*BB*HH;            // [2, 64, 1024]

    // workspace layout (floats)
    float* ws     = (float*)d_ws;
    float* Acat0  = ws;                       // [64, 2048]  = [emb ; h0[0]]
    float* Acat1  = Acat0 + 131072;           // [64, 2048]  = [h1 ; h0[1]]
    float* Acat3  = Acat1 + 131072;           // [64, 2048]  = [context ; h_top]
    float* gates  = Acat3 + 131072;           // [SLSTM=8][64, 4096] partials
    float* catP   = gates;                    // [SCAT=8][64, 1024] (aliases gates; disjoint lifetime)
    float* h_c    = gates + SLSTM*262144;     // [64, 1024]
    float* u_e    = h_c   + 65536;            // [1024]
    float* scores = u_e   + 1024;             // [64, 128]
    float* Pout   = scores + 8192;            // [2][64][32000] split-K partials
    float2* ms    = (float2*)(Pout + 2*BB*VV);// [64][4] (m, s) pairs

    // 1) embedding gather + A_cat prep + attention u_e (independent, fused)
    prep_attn<<<272, 256, 0, stream>>>(tokens, emb, h0, attn_W, attn_v,
                                       Acat0, Acat1, u_e);

    // 2) LSTM layer 0: gates = Acat0 @ [W_ih0 | W_hh0]^T  (split-K S=8, kChunk=256)
    gemm_bf<0><<<dim3(32, SLSTM), 256, 0, stream>>>(Acat0, 2048,
                                      W_ih, W_hh, 1024, 1024,
                                      256, 4096, nullptr, gates);
    lstm_point<<<256, 256, 0, stream>>>(gates, b_ih, b_hh, c0,
                                        h_n, c_n, Acat1, 0);

    // 3) LSTM layer 1
    gemm_bf<0><<<dim3(32, SLSTM), 256, 0, stream>>>(Acat1, 2048,
                                      W_ih + (size_t)4096*1024,
                                      W_hh + (size_t)4096*1024, 1024, 1024,
                                      256, 4096, nullptr, gates);
    lstm_point<<<256, 256, 0, stream>>>(gates, b_ih + 4096, b_hh + 4096, c0 + BB*HH,
                                        h_n + BB*HH, c_n + BB*HH, Acat3, 1024);

    // 4) scores (only encoder term survives the softmax) + fused softmax/context
    scores_kernel<<<2048, 256, 0, stream>>>(u_e, enc, scores);
    smctx_kernel<<<256, 256, 0, stream>>>(scores, enc, Acat3);

    // 5) concat partials = Acat3 @ concat_W^T  (split-K S=8, kChunk=256)
    gemm_bf<0><<<dim3(8, SCAT), 256, 0, stream>>>(Acat3, 2048,
                                      concat_W, nullptr, 1 << 30, 2048,
                                      256, 1024, nullptr, catP);
    reduce_tanh<<<256, 256, 0, stream>>>(catP, concat_b, h_c);

    // 6) logits partials = h_c @ out_W^T  (split-K S=2, kChunk=512, 500 blocks)
    gemm_bf<0><<<dim3(250, 2), 256, 0, stream>>>(h_c, 1024,
                                      out_W, nullptr, 1 << 30, 1024,
                                      512, VV, nullptr, Pout);

    // 7) reduce partials + bias -> logits (in d_out) + chunk-wise (max,sum)
    lse_part<<<dim3(4, 64), 256, 0, stream>>>(Pout, out_b, logp, ms);

    // 8) combine lse, subtract in place
    sub_final<<<dim3(32, 64), 256, 0, stream>>>(logp, ms);
}

// Round 8
// 132.037 us; speedup vs baseline: 1.2421x; 1.1640x over previous
//
#include <hip/hip_runtime.h>
#include <math.h>

#define BB 64
#define HH 1024
#define VV 32000
#define SRC 128
#define SLSTM 8
#define SCAT 8

typedef __attribute__((ext_vector_type(8))) __bf16 bf16x8;
typedef __attribute__((ext_vector_type(8))) unsigned short ushort8;
typedef __attribute__((ext_vector_type(4))) float f32x4;

__device__ __forceinline__ float sigmoidf_(float x){ return 1.f/(1.f+expf(-x)); }

__device__ __forceinline__ unsigned short f2bf(float f){
    union { float f; unsigned u; } v; v.f = f;
    unsigned r = v.u + 0x7FFFu + ((v.u >> 16) & 1u);   // round-to-nearest-even
    return (unsigned short)(r >> 16);
}

__device__ __forceinline__ void cvt8(const float4& x, const float4& y, unsigned short* dst){
    ushort8 s;
    s[0]=f2bf(x.x); s[1]=f2bf(x.y); s[2]=f2bf(x.z); s[3]=f2bf(x.w);
    s[4]=f2bf(y.x); s[5]=f2bf(y.y); s[6]=f2bf(y.z); s[7]=f2bf(y.w);
    *(ushort8*)dst = s;
}

// ============ MFMA GEMM: C[64,N] = [A0|A1][64,2048] @ W[N,K]^T, split-K S=8 ============
// A given as two row-major [64,1024] sources split at k=1024 (GATHER: A0 row = tokens[m]).
// W split at global-k K0 into B0/B1 (for [W_ih|W_hh]). kChunk=256. grid=(N/128, 8 [+extra]).
// EXTRA==1: blockIdx.y==8, x<16 -> u_e = (attn_W^T v)[1024:2048]
// EXTRA==2: blockIdx.y in 8..15 -> fused softmax(scores)+context
template<int GATHER, int EXTRA>
__global__ __launch_bounds__(256)
void gemm_bf(const int* __restrict__ tokens,
             const float* __restrict__ A0, const float* __restrict__ A1,
             const float* __restrict__ B0, const float* __restrict__ B1,
             int K0, int ldb, int kChunk, int N, float* __restrict__ C,
             const float* __restrict__ xa, const float* __restrict__ xb,
             float* __restrict__ xo)
{
    // padded row stride 72 shorts (144 B): 16B-aligned rows
    __shared__ __align__(16) unsigned short As[2][64*72];
    __shared__ __align__(16) unsigned short Bs[2][128*72];
    const int tid = threadIdx.x;

    if (EXTRA && blockIdx.y >= 8) {
        if (EXTRA == 1) {               // u_e[k] = sum_h attn_v[h] * attn_W[h][1024+k]
            if (blockIdx.x >= 16) return;
            float4 (*red)[17] = (float4 (*)[17])As;
            int kq = tid & 15, hp = tid >> 4;
            int k = 1024 + blockIdx.x*64 + kq*4;
            float4 s = {0.f,0.f,0.f,0.f};
            for (int h = hp; h < HH; h += 16) {
                float vh = xb[h];
                float4 w = *(const float4*)&xa[(size_t)h*2048 + k];
                s.x = fmaf(vh, w.x, s.x); s.y = fmaf(vh, w.y, s.y);
                s.z = fmaf(vh, w.z, s.z); s.w = fmaf(vh, w.w, s.w);
            }
            red[hp][kq] = s;
            __syncthreads();
            if (tid < 16) {
                float4 t = {0.f,0.f,0.f,0.f};
                #pragma unroll
                for (int i = 0; i < 16; ++i) {
                    float4 r = red[i][tid];
                    t.x += r.x; t.y += r.y; t.z += r.z; t.w += r.w;
                }
                *(float4*)&xo[blockIdx.x*64 + tid*4] = t;
            }
        } else {                        // smctx: softmax over scores row + context
            float* wl = (float*)As;
            int sid = (blockIdx.y - 8)*32 + blockIdx.x;   // 0..255
            int b = sid >> 2;
            int h = ((sid & 3) << 8) + tid;
            if (tid < SRC) wl[tid] = xa[b*SRC + tid];
            __syncthreads();
            float m = -INFINITY;
            #pragma unroll 8
            for (int l = 0; l < SRC; ++l) m = fmaxf(m, wl[l]);
            float sum = 0.f;
            #pragma unroll 8
            for (int l = 0; l < SRC; ++l) sum += expf(wl[l] - m);
            float inv = 1.f / sum;
            __syncthreads();
            if (tid < SRC) wl[tid] = expf(wl[tid] - m) * inv;
            __syncthreads();
            float acc = 0.f;
            #pragma unroll 4
            for (int l = 0; l < SRC; ++l)
                acc = fmaf(wl[l], xb[(size_t)(l*BB + b)*HH + h], acc);
            xo[b*HH + h] = acc;
        }
        return;
    }

    const int n0 = blockIdx.x * 128;
    const int kbase = blockIdx.y * kChunk;
    const int nt = kChunk >> 6;
    const int am = tid >> 2, ak = (tid & 3) << 4;   // A stage: row, 16-float k chunk
    const int bn = tid >> 1, bk = (tid & 1) << 5;   // B stage: row, 32-float k chunk
    int arow = am;
    if (GATHER) arow = tokens[am];

    f32x4 acc[4][2] = {};
    float4 aR[4], bR[8];

    auto loadG = [&](int t){
        int ka = kbase + (t << 6) + ak;             // 16-float chunk, never straddles 1024
        const float* Ap = (ka < 1024) ? (A0 + (size_t)arow*HH + ka)
                                      : (A1 + (size_t)am*HH + (ka - 1024));
        #pragma unroll
        for (int i = 0; i < 4; ++i) aR[i] = *(const float4*)(Ap + i*4);
        int k0g = kbase + (t << 6);
        const float* Bp; int kb;
        if (k0g < K0) { Bp = B0; kb = k0g; } else { Bp = B1; kb = k0g - K0; }
        const float* Bq = Bp + (size_t)(n0 + bn) * ldb + kb + bk;
        #pragma unroll
        for (int i = 0; i < 8; ++i) bR[i] = *(const float4*)(Bq + i*4);
    };
    auto writeL = [&](int buf){
        cvt8(aR[0], aR[1], &As[buf][am*72 + ak]);
        cvt8(aR[2], aR[3], &As[buf][am*72 + ak + 8]);
        #pragma unroll
        for (int h = 0; h < 4; ++h)
            cvt8(bR[h*2], bR[h*2+1], &Bs[buf][bn*72 + bk + h*8]);
    };

    loadG(0);
    writeL(0);
    __syncthreads();

    const int lane = tid & 63;
    const int wn = (tid >> 6) << 5;           // wave's 32-wide N strip
    const int lr = lane >> 4, lc = lane & 15;

    for (int t = 0; t < nt; ++t) {
        const int cur = t & 1;
        if (t + 1 < nt) loadG(t + 1);
        #pragma unroll
        for (int ks = 0; ks < 2; ++ks) {
            bf16x8 aF[4], bF[2];
            #pragma unroll
            for (int fm = 0; fm < 4; ++fm)
                aF[fm] = *(const bf16x8*)&As[cur][(fm*16 + lc)*72 + ks*32 + lr*8];
            #pragma unroll
            for (int fn = 0; fn < 2; ++fn)
                bF[fn] = *(const bf16x8*)&Bs[cur][(wn + fn*16 + lc)*72 + ks*32 + lr*8];
            #pragma unroll
            for (int fm = 0; fm < 4; ++fm)
                #pragma unroll
                for (int fn = 0; fn < 2; ++fn)
                    acc[fm][fn] = __builtin_amdgcn_mfma_f32_16x16x32_bf16(
                        aF[fm], bF[fn], acc[fm][fn], 0, 0, 0);
        }
        if (t + 1 < nt) {
            writeL((t + 1) & 1);
            __syncthreads();
        }
    }

    float* Cp = C + (size_t)blockIdx.y * 64 * N;    // raw split-K partial
    #pragma unroll
    for (int fn = 0; fn < 2; ++fn) {
        int n = n0 + wn + fn*16 + lc;
        #pragma unroll
        for (int fm = 0; fm < 4; ++fm)
            #pragma unroll
            for (int r = 0; r < 4; ++r)
                Cp[(size_t)(fm*16 + lr*4 + r)*N + n] = acc[fm][fn][r];
    }
}

// ====== out-projection: logits[64,32000] = h_c @ out_W^T + b; fused row (m,s) partials ======
// 250 blocks x 512 threads (8 waves); N-tile 128 (wave owns 16 cols), K=1024, BK=64.
__global__ __launch_bounds__(512)
void out_gemm(const float* __restrict__ A, const float* __restrict__ W,
              const float* __restrict__ bias, float* __restrict__ logits,
              float2* __restrict__ ms)
{
    __shared__ __align__(16) unsigned short As[2][64*72];
    __shared__ __align__(16) unsigned short Bs[2][128*72];
    __shared__ float wm[8][64], wsum[8][64];
    const int tid = threadIdx.x;
    const int n0 = blockIdx.x * 128;
    const int am = tid >> 3, ak = (tid & 7) << 3;   // 64 rows x 8-float chunks
    const int bn = tid >> 2, bk = (tid & 3) << 4;   // 128 rows x 16-float chunks

    f32x4 acc[4] = {};
    float4 aR[2], bR[4];

    auto loadG = [&](int t){
        int k0 = t << 6;
        const float* Ap = A + (size_t)am*HH + k0 + ak;
        aR[0] = *(const float4*)(Ap);
        aR[1] = *(const float4*)(Ap + 4);
        const float* Wp = W + (size_t)(n0 + bn)*HH + k0 + bk;
        #pragma unroll
        for (int i = 0; i < 4; ++i) bR[i] = *(const float4*)(Wp + i*4);
    };
    auto writeL = [&](int buf){
        cvt8(aR[0], aR[1], &As[buf][am*72 + ak]);
        cvt8(bR[0], bR[1], &Bs[buf][bn*72 + bk]);
        cvt8(bR[2], bR[3], &Bs[buf][bn*72 + bk + 8]);
    };

    loadG(0);
    writeL(0);
    __syncthreads();

    const int lane = tid & 63, w = tid >> 6;
    const int lr = lane >> 4, lc = lane & 15;

    for (int t = 0; t < 16; ++t) {
        const int cur = t & 1;
        if (t + 1 < 16) loadG(t + 1);
        #pragma unroll
        for (int ks = 0; ks < 2; ++ks) {
            bf16x8 bF = *(const bf16x8*)&Bs[cur][(w*16 + lc)*72 + ks*32 + lr*8];
            #pragma unroll
            for (int fm = 0; fm < 4; ++fm) {
                bf16x8 aF = *(const bf16x8*)&As[cur][(fm*16 + lc)*72 + ks*32 + lr*8];
                acc[fm] = __builtin_amdgcn_mfma_f32_16x16x32_bf16(aF, bF, acc[fm], 0, 0, 0);
            }
        }
        if (t + 1 < 16) {
            writeL((t + 1) & 1);
            __syncthreads();
        }
    }

    // epilogue: bias, write logits, per-row (max, expsum) partials for this block's 128 cols
    const int n = n0 + w*16 + lc;
    const float bv = bias[n];
    #pragma unroll
    for (int fm = 0; fm < 4; ++fm) {
        #pragma unroll
        for (int r = 0; r < 4; ++r) {
            float v = acc[fm][r] + bv;
            logits[(size_t)(fm*16 + lr*4 + r)*VV + n] = v;
            // reduce over the 16 lanes (lc) sharing this (w, lr) -> over wave's 16 cols
            float mx = v;
            #pragma unroll
            for (int o = 1; o < 16; o <<= 1) mx = fmaxf(mx, __shfl_xor(mx, o));
            float se = expf(v - mx);
            #pragma unroll
            for (int o = 1; o < 16; o <<= 1) se += __shfl_xor(se, o);
            if (lc == 0) {
                int m = fm*16 + lr*4 + r;
                wm[w][m] = mx;
                wsum[w][m] = se;
            }
        }
    }
    __syncthreads();
    if (tid < 64) {
        float M = wm[0][tid];
        #pragma unroll
        for (int i = 1; i < 8; ++i) M = fmaxf(M, wm[i][tid]);
        float S = 0.f;
        #pragma unroll
        for (int i = 0; i < 8; ++i) S += wsum[i][tid] * expf(wm[i][tid] - M);
        ms[blockIdx.x*64 + tid] = make_float2(M, S);
    }
}

// ---------------- LSTM pointwise (+ optional fused attention scores) ----------------
template<int WITH_SCORES>
__global__ __launch_bounds__(256)
void lstm_point(const float* __restrict__ gates,   // [SLSTM][64][4096]
                const float* __restrict__ bih, const float* __restrict__ bhh,
                const float* __restrict__ c0,
                float* __restrict__ hn, float* __restrict__ cn,
                float* __restrict__ hout,
                const float* __restrict__ u_e, const float* __restrict__ enc,
                float* __restrict__ scores)
{
    int bid = blockIdx.x;
    if (WITH_SCORES && bid >= 256) {
        // scores[b,l] = u_e . enc[l,b,:]  (h/bias score terms cancel in softmax)
        int g = (bid - 256)*4 + (threadIdx.x >> 6);   // 0..2047, 4 pairs each
        int lane = threadIdx.x & 63;
        #pragma unroll
        for (int q = 0; q < 4; ++q) {
            int p = g*4 + q;
            int b = p >> 7, l = p & 127;
            const float* e = enc + (size_t)(l*BB + b)*HH;
            float s = 0.f;
            #pragma unroll
            for (int t = 0; t < 16; ++t)
                s = fmaf(u_e[lane + 64*t], e[lane + 64*t], s);
            #pragma unroll
            for (int o = 32; o > 0; o >>= 1) s += __shfl_xor(s, o);
            if (lane == 0) scores[b*SRC + l] = s;
        }
        return;
    }
    int idx = bid*256 + threadIdx.x;     // 0..65535
    int b = idx >> 10, k = idx & 1023;
    const float* g = gates + b*4096;
    float ig = bih[k]        + bhh[k];
    float fg = bih[1024 + k] + bhh[1024 + k];
    float gg = bih[2048 + k] + bhh[2048 + k];
    float og = bih[3072 + k] + bhh[3072 + k];
    #pragma unroll
    for (int s = 0; s < SLSTM; ++s) {
        const float* gs = g + s*BB*4096;
        ig += gs[k];
        fg += gs[1024 + k];
        gg += gs[2048 + k];
        og += gs[3072 + k];
    }
    float c = sigmoidf_(fg)*c0[b*HH + k] + sigmoidf_(ig)*tanhf(gg);
    float h = sigmoidf_(og)*tanhf(c);
    cn[b*HH + k] = c;
    hn[b*HH + k] = h;
    hout[b*HH + k] = h;
}

// ---------------- concat reduce + bias + tanh (SCAT partials) ----------------
__global__ __launch_bounds__(256)
void reduce_tanh(const float* __restrict__ P,   // [SCAT][64][1024]
                 const float* __restrict__ bias, float* __restrict__ out)
{
    int idx = blockIdx.x*256 + threadIdx.x;     // 0..65535
    int n = idx & 1023;
    float s = bias[n];
    #pragma unroll
    for (int si = 0; si < SCAT; ++si) s += P[si*65536 + idx];
    out[idx] = tanhf(s);
}

// ------- merge 250 per-block (m,s) partials -> lse[b]; subtract in place -------
__global__ __launch_bounds__(256)
void sub_final(float* __restrict__ logp, const float2* __restrict__ ms)
{
    __shared__ float2 red[256];
    int b = blockIdx.y;
    float m = -INFINITY, s = 0.f;
    if (threadIdx.x < 250) {
        float2 p = ms[threadIdx.x*64 + b];
        m = p.x; s = p.y;
    }
    red[threadIdx.x] = make_float2(m, s);
    __syncthreads();
    for (int o = 128; o > 0; o >>= 1) {
        if (threadIdx.x < o) {
            float2 a = red[threadIdx.x], c = red[threadIdx.x + o];
            float M = fmaxf(a.x, c.x);
            float S = a.y * expf(a.x - M) + c.y * expf(c.x - M);
            red[threadIdx.x] = make_float2(M, S);
        }
        __syncthreads();
    }
    float lse = red[0].x + logf(red[0].y);
    int i = blockIdx.x*256 + threadIdx.x;       // over 8000 float4
    if (i < 8000) {
        float4* p = (float4*)(logp + (size_t)b*VV);
        float4 v = p[i];
        v.x -= lse; v.y -= lse; v.z -= lse; v.w -= lse;
        p[i] = v;
    }
}

// ================================================================
extern "C" void kernel_launch(void* const* d_in, const int* in_sizes, int n_in,
                              void* d_out, int out_size, void* d_ws, size_t ws_size,
                              hipStream_t stream)
{
    const int*   tokens   = (const int*)  d_in[0];
    const float* h0       = (const float*)d_in[1];
    const float* c0       = (const float*)d_in[2];
    const float* enc      = (const float*)d_in[3];
    const float* emb      = (const float*)d_in[4];
    const float* W_ih     = (const float*)d_in[5];
    const float* W_hh     = (const float*)d_in[6];
    const float* b_ih     = (const float*)d_in[7];
    const float* b_hh     = (const float*)d_in[8];
    const float* attn_W   = (const float*)d_in[9];
    const float* attn_v   = (const float*)d_in[11];
    const float* concat_W = (const float*)d_in[12];
    const float* concat_b = (const float*)d_in[13];
    const float* out_W    = (const float*)d_in[14];
    const float* out_b    = (const float*)d_in[15];

    float* out  = (float*)d_out;
    float* logp = out;                      // [64, 32000]
    float* h_n  = out + (size_t)BB*VV;      // [2, 64, 1024]
    float* c_n  = h_n + 2*BB*HH;            // [2, 64, 1024]

    // workspace layout (floats)
    float* ws     = (float*)d_ws;
    float* gates  = ws;                       // [SLSTM=8][64][4096] partials (8.4 MB)
    float* catP   = gates;                    // [SCAT=8][64][1024] (aliases; disjoint lifetime)
    float* h1     = gates + SLSTM*262144;     // [64][1024] layer-0 hidden
    float* h_top  = h1    + 65536;            // [64][1024] layer-1 hidden
    float* ctx    = h_top + 65536;            // [64][1024] attention context
    float* h_c    = ctx   + 65536;            // [64][1024] concat output
    float* u_e    = h_c   + 65536;            // [1024]
    float* scores = u_e   + 1024;             // [64][128]
    float2* ms    = (float2*)(scores + 8192); // [250][64] (m, s)

    // 1) LSTM L0 GEMM (A = [emb[tok] ; h0[0]] gathered inline) + u_e side-blocks
    gemm_bf<1,1><<<dim3(32, 9), 256, 0, stream>>>(
        tokens, emb, h0, W_ih, W_hh, 1024, 1024, 256, 4096, gates,
        attn_W, attn_v, u_e);

    // 2) LSTM L0 pointwise + attention scores (independent; fused grid)
    lstm_point<1><<<768, 256, 0, stream>>>(gates, b_ih, b_hh, c0,
                                           h_n, c_n, h1, u_e, enc, scores);

    // 3) LSTM L1 GEMM (A = [h1 ; h0[1]]) + fused softmax/context side-blocks
    gemm_bf<0,2><<<dim3(32, 16), 256, 0, stream>>>(
        nullptr, h1, h0 + BB*HH,
        W_ih + (size_t)4096*1024, W_hh + (size_t)4096*1024, 1024, 1024,
        256, 4096, gates, scores, enc, ctx);

    // 4) LSTM L1 pointwise
    lstm_point<0><<<256, 256, 0, stream>>>(gates, b_ih + 4096, b_hh + 4096, c0 + BB*HH,
                                           h_n + BB*HH, c_n + BB*HH, h_top,
                                           nullptr, nullptr, nullptr);

    // 5) concat GEMM (A = [ctx ; h_top]) -> partials
    gemm_bf<0,0><<<dim3(8, 8), 256, 0, stream>>>(
        nullptr, ctx, h_top, concat_W, nullptr, 1 << 30, 2048,
        256, 1024, catP, nullptr, nullptr, nullptr);

    // 6) reduce + bias + tanh -> h_c
    reduce_tanh<<<256, 256, 0, stream>>>(catP, concat_b, h_c);

    // 7) out-projection: logits (+bias) direct to d_out + per-block row (m,s) partials
    out_gemm<<<250, 512, 0, stream>>>(h_c, out_W, out_b, logp, ms);

    // 8) merge partials -> lse, subtract in place
    sub_final<<<dim3(32, 64), 256, 0, stream>>>(logp, ms);
}